// Round 1
// baseline (255.089 us; speedup 1.0000x reference)
//
#include <hip/hip_runtime.h>
#include <math.h>

#define NB  4
#define NLQ 256
#define NLK 512
#define NH  256

// ---------------------------------------------------------------------------
// Projection: out[r,h] = bias[h] + sum_c X[r,c] * W[h,c]   (y = x @ W^T + b)
// Block = 256 threads, handles 8 rows. Thread t owns output column h = t.
// X rows staged in LDS (broadcast reads); W row streamed per-thread as float4.
// ---------------------------------------------------------------------------
__global__ __launch_bounds__(256) void proj_kernel(
    const float* __restrict__ X, const float* __restrict__ W,
    const float* __restrict__ bias, float* __restrict__ out)
{
    const int ROWS = 8;
    __shared__ float xs[ROWS][NH];
    const int r0 = blockIdx.x * ROWS;
    const int t  = threadIdx.x;

    const float4* Xv  = (const float4*)(X + (size_t)r0 * NH);
    float4*       xsv = (float4*)&xs[0][0];
    #pragma unroll
    for (int i = 0; i < (ROWS * NH / 4) / 256; ++i)
        xsv[t + i * 256] = Xv[t + i * 256];
    __syncthreads();

    float acc[ROWS];
    const float bb = bias[t];
    #pragma unroll
    for (int r = 0; r < ROWS; ++r) acc[r] = bb;

    const float4* Wv = (const float4*)(W + (size_t)t * NH);
    #pragma unroll 4
    for (int c4 = 0; c4 < NH / 4; ++c4) {
        float4 w = Wv[c4];
        #pragma unroll
        for (int r = 0; r < ROWS; ++r) {
            float4 x = ((const float4*)xs[r])[c4];
            acc[r] = fmaf(x.x, w.x, acc[r]);
            acc[r] = fmaf(x.y, w.y, acc[r]);
            acc[r] = fmaf(x.z, w.z, acc[r]);
            acc[r] = fmaf(x.w, w.w, acc[r]);
        }
    }
    #pragma unroll
    for (int r = 0; r < ROWS; ++r)
        out[(size_t)(r0 + r) * NH + t] = acc[r];
}

// ---------------------------------------------------------------------------
// tanh via exp2 + rcp (raw v_exp_f32 / v_rcp_f32, ~1 ulp each)
// ---------------------------------------------------------------------------
__device__ __forceinline__ float fast_tanh(float x) {
    x = fminf(15.0f, fmaxf(-15.0f, x));
    float e = __builtin_amdgcn_exp2f(x * 2.885390081777927f); // exp(2x)
    return (e - 1.0f) * __builtin_amdgcn_rcpf(e + 1.0f);
}

// ---------------------------------------------------------------------------
// Fused scores + softmax + output. Block = 256 threads (4 waves), QT=2 query
// rows per block. Grid = B*LQ/2 = 512 blocks.
// Scores: wave w owns k in [w*128, (w+1)*128); lane l owns h in {4l..4l+3}
//   -> one coalesced float4 wave-load per kp row; butterfly-reduce over lanes.
// Masked k (mask==0, wave-uniform) skip tanh + load entirely.
// Softmax: wave q handles row q (8 elems/lane, shuffle reductions).
// Output: thread t = column h; k-loop with LDS-broadcast weights.
// ---------------------------------------------------------------------------
__global__ __launch_bounds__(256) void attn_kernel(
    const float* __restrict__ qp, const float* __restrict__ kp,
    const float* __restrict__ value, const int* __restrict__ mask,
    const float* __restrict__ vvec, const float* __restrict__ bvp,
    float* __restrict__ out_o, float* __restrict__ out_w)
{
    const int QT = 2;
    __shared__ float sc[QT][NLK];

    const int blk  = blockIdx.x;
    const int b    = blk / (NLQ / QT);
    const int q0   = (blk % (NLQ / QT)) * QT;
    const int t    = threadIdx.x;
    const int lane = t & 63;
    const int wave = t >> 6;
    const float bv = bvp[0];

    const float4 vf = ((const float4*)vvec)[lane];
    const float4 qa = ((const float4*)(qp + (size_t)(b * NLQ + q0)     * NH))[lane];
    const float4 qb = ((const float4*)(qp + (size_t)(b * NLQ + q0 + 1) * NH))[lane];

    const int*   mrow  = mask + b * NLK;
    const float* kprow = kp + (size_t)b * NLK * NH;

    const int KPW   = NLK / 4;        // 128 k per wave
    const int kbase = wave * KPW;

    for (int kk = 0; kk < KPW; ++kk) {
        const int k = kbase + kk;
        if (mrow[k] == 0) {
            if (lane == 0) { sc[0][k] = -INFINITY; sc[1][k] = -INFINITY; }
            continue;
        }
        const float4 kf = ((const float4*)(kprow + (size_t)k * NH))[lane];

        float p0 = vf.x * fast_tanh(qa.x + kf.x);
        p0 = fmaf(vf.y, fast_tanh(qa.y + kf.y), p0);
        p0 = fmaf(vf.z, fast_tanh(qa.z + kf.z), p0);
        p0 = fmaf(vf.w, fast_tanh(qa.w + kf.w), p0);

        float p1 = vf.x * fast_tanh(qb.x + kf.x);
        p1 = fmaf(vf.y, fast_tanh(qb.y + kf.y), p1);
        p1 = fmaf(vf.z, fast_tanh(qb.z + kf.z), p1);
        p1 = fmaf(vf.w, fast_tanh(qb.w + kf.w), p1);

        #pragma unroll
        for (int m = 32; m >= 1; m >>= 1) {
            p0 += __shfl_xor(p0, m, 64);
            p1 += __shfl_xor(p1, m, 64);
        }
        if (lane == 0) { sc[0][k] = p0 + bv; sc[1][k] = p1 + bv; }
    }
    __syncthreads();

    // ---- softmax: wave 0 -> row 0, wave 1 -> row 1 ----
    if (wave < QT) {
        float* row = sc[wave];
        float vals[8];
        float m = -INFINITY;
        #pragma unroll
        for (int j = 0; j < 8; ++j) {
            vals[j] = row[lane + j * 64];
            m = fmaxf(m, vals[j]);
        }
        #pragma unroll
        for (int s = 32; s >= 1; s >>= 1)
            m = fmaxf(m, __shfl_xor(m, s, 64));
        float sum = 0.0f;
        #pragma unroll
        for (int j = 0; j < 8; ++j) {
            vals[j] = __builtin_amdgcn_exp2f((vals[j] - m) * 1.4426950408889634f);
            sum += vals[j];
        }
        #pragma unroll
        for (int s = 32; s >= 1; s >>= 1)
            sum += __shfl_xor(sum, s, 64);
        const float inv = __builtin_amdgcn_rcpf(sum);
        float* wout = out_w + (size_t)(b * NLQ + q0 + wave) * NLK;
        #pragma unroll
        for (int j = 0; j < 8; ++j) {
            const float wv = vals[j] * inv;
            row[lane + j * 64]  = wv;
            wout[lane + j * 64] = wv;
        }
    }
    __syncthreads();

    // ---- output: attn_out[b, q0+{0,1}, h=t] = sum_k w[k] * value[b,k,h] ----
    const float* vrow = value + (size_t)b * NLK * NH + t;
    float acc0 = 0.0f, acc1 = 0.0f;
    for (int k = 0; k < NLK; ++k) {
        if (mrow[k] == 0) continue;           // block-uniform branch
        const float val = vrow[(size_t)k * NH];
        acc0 = fmaf(sc[0][k], val, acc0);
        acc1 = fmaf(sc[1][k], val, acc1);
    }
    out_o[(size_t)(b * NLQ + q0)     * NH + t] = acc0;
    out_o[(size_t)(b * NLQ + q0 + 1) * NH + t] = acc1;
}

// ---------------------------------------------------------------------------
extern "C" void kernel_launch(void* const* d_in, const int* in_sizes, int n_in,
                              void* d_out, int out_size, void* d_ws, size_t ws_size,
                              hipStream_t stream) {
    const float* query = (const float*)d_in[0];
    const float* key   = (const float*)d_in[1];
    const float* value = (const float*)d_in[2];
    const int*   mask  = (const int*)  d_in[3];
    const float* Wq    = (const float*)d_in[4];
    const float* bq    = (const float*)d_in[5];
    const float* Wk    = (const float*)d_in[6];
    const float* bk    = (const float*)d_in[7];
    const float* v     = (const float*)d_in[8];
    const float* bv    = (const float*)d_in[9];

    float* out_o = (float*)d_out;                 // [4,256,256]
    float* out_w = out_o + NB * NLQ * NH;         // [4,256,512]

    float* qp = (float*)d_ws;                     // [4,256,256]
    float* kp = qp + NB * NLQ * NH;               // [4,512,256]

    proj_kernel<<<NB * NLQ / 8, 256, 0, stream>>>(query, Wq, bq, qp);
    proj_kernel<<<NB * NLK / 8, 256, 0, stream>>>(key,   Wk, bk, kp);
    attn_kernel<<<NB * NLQ / 2, 256, 0, stream>>>(qp, kp, value, mask, v, bv, out_o, out_w);
}

// Round 2
// 159.070 us; speedup vs baseline: 1.6036x; 1.6036x over previous
//
#include <hip/hip_runtime.h>
#include <math.h>

#define NB  4
#define NLQ 256
#define NLK 512
#define NH  256

// scale folded into projections: exp2(SC*(q+k)) = exp(2*(q+k))
#define SCALE_2LOG2E 2.885390081777927f
#define LOG2E        1.4426950408889634f

// ---------------------------------------------------------------------------
// Mask compaction: act[b][j] = j-th active k index, nact[b] = count.
// One wave per batch, ballot prefix-scan.
// ---------------------------------------------------------------------------
__global__ __launch_bounds__(64) void compact_kernel(
    const int* __restrict__ mask, int* __restrict__ act, int* __restrict__ nact)
{
    const int b    = blockIdx.x;
    const int lane = threadIdx.x;
    const int* m   = mask + b * NLK;
    int base = 0;
    #pragma unroll
    for (int g = 0; g < NLK / 64; ++g) {
        const int k = g * 64 + lane;
        const bool a = (m[k] != 0);
        const unsigned long long bal = __ballot(a);
        const int pos = base + __popcll(bal & ((1ULL << lane) - 1ULL));
        if (a) act[b * NLK + pos] = k;
        base += __popcll(bal);
    }
    if (lane == 0) nact[b] = base;
}

// ---------------------------------------------------------------------------
// Q projection: out[r,h] = SC * (bias[h] + sum_c X[r,c]*W[h,c]); ROWS=4.
// ---------------------------------------------------------------------------
__global__ __launch_bounds__(256) void qproj_kernel(
    const float* __restrict__ X, const float* __restrict__ W,
    const float* __restrict__ bias, float* __restrict__ out)
{
    const int ROWS = 4;
    __shared__ float xs[ROWS][NH];
    const int r0 = blockIdx.x * ROWS;
    const int t  = threadIdx.x;

    ((float4*)&xs[0][0])[t] = ((const float4*)(X + (size_t)r0 * NH))[t];
    __syncthreads();

    float acc[ROWS];
    const float bb = bias[t];
    #pragma unroll
    for (int r = 0; r < ROWS; ++r) acc[r] = bb;

    const float4* Wv = (const float4*)(W + (size_t)t * NH);
    #pragma unroll 4
    for (int c4 = 0; c4 < NH / 4; ++c4) {
        const float4 w = Wv[c4];
        #pragma unroll
        for (int r = 0; r < ROWS; ++r) {
            const float4 x = ((const float4*)xs[r])[c4];
            acc[r] = fmaf(x.x, w.x, acc[r]);
            acc[r] = fmaf(x.y, w.y, acc[r]);
            acc[r] = fmaf(x.z, w.z, acc[r]);
            acc[r] = fmaf(x.w, w.w, acc[r]);
        }
    }
    #pragma unroll
    for (int r = 0; r < ROWS; ++r)
        out[(size_t)(r0 + r) * NH + t] = acc[r] * SCALE_2LOG2E;
}

// ---------------------------------------------------------------------------
// K projection over COMPACTED active rows only. Block covers 4 compact slots
// of one batch; early-exit if slot range fully beyond nact[b].
// ---------------------------------------------------------------------------
__global__ __launch_bounds__(256) void kproj_kernel(
    const float* __restrict__ X, const float* __restrict__ W,
    const float* __restrict__ bias, const int* __restrict__ act,
    const int* __restrict__ nact, float* __restrict__ out)
{
    const int ROWS = 4;
    const int b  = blockIdx.x / (NLK / ROWS);         // 128 blocks per batch
    const int j0 = (blockIdx.x % (NLK / ROWS)) * ROWS;
    const int na = nact[b];
    if (j0 >= na) return;

    __shared__ float xs[ROWS][NH];
    __shared__ int   ridx[ROWS];
    const int t = threadIdx.x;
    if (t < ROWS)
        ridx[t] = act[b * NLK + ((j0 + t < na) ? (j0 + t) : j0)];
    __syncthreads();

    {   // stage 4 source rows (gathered by original k index)
        const int r = t >> 6, c4 = t & 63;
        ((float4*)xs[r])[c4] =
            ((const float4*)(X + ((size_t)b * NLK + ridx[r]) * NH))[c4];
    }
    __syncthreads();

    float acc[ROWS];
    const float bb = bias[t];
    #pragma unroll
    for (int r = 0; r < ROWS; ++r) acc[r] = bb;

    const float4* Wv = (const float4*)(W + (size_t)t * NH);
    #pragma unroll 4
    for (int c4 = 0; c4 < NH / 4; ++c4) {
        const float4 w = Wv[c4];
        #pragma unroll
        for (int r = 0; r < ROWS; ++r) {
            const float4 x = ((const float4*)xs[r])[c4];
            acc[r] = fmaf(x.x, w.x, acc[r]);
            acc[r] = fmaf(x.y, w.y, acc[r]);
            acc[r] = fmaf(x.z, w.z, acc[r]);
            acc[r] = fmaf(x.w, w.w, acc[r]);
        }
    }
    #pragma unroll
    for (int r = 0; r < ROWS; ++r)
        if (j0 + r < na)
            out[((size_t)b * NLK + j0 + r) * NH + t] = acc[r] * SCALE_2LOG2E;
}

// ---------------------------------------------------------------------------
// Fused scores + softmax + output. Block = 256 threads, QT=2 q-rows,
// thread t owns compact k-columns {t, t+256}. No cross-lane reductions in
// the score loop; 4 independent accumulator chains per thread.
// score(q,k) = const - 2*sum_h v[h]*rcp(exp2(q'[h]+k'[h])+1); const drops
// out of softmax (shift invariance).
// ---------------------------------------------------------------------------
#define TH 16
__global__ __launch_bounds__(256) void attn_kernel(
    const float* __restrict__ qp, const float* __restrict__ kp,
    const float* __restrict__ value, const int* __restrict__ act,
    const int* __restrict__ nact, const float* __restrict__ vvec,
    float* __restrict__ out_o, float* __restrict__ out_w)
{
    __shared__ float qs[2][NH];         // scaled q rows
    __shared__ float vs[NH];            // v vector
    __shared__ float kt[NLK][TH + 1];   // staged kp tile, pad 17 (conflict-free)
    __shared__ float sc[2][NLK];        // scores -> weights
    __shared__ int   actl[NLK];

    const int blk = blockIdx.x;
    const int b   = blk >> 7;             // 128 blocks per batch (LQ/2)
    const int q0  = (blk & 127) * 2;
    const int t   = threadIdx.x;
    const int na  = nact[b];

    qs[0][t]      = qp[((size_t)(b * NLQ + q0)    ) * NH + t];
    qs[1][t]      = qp[((size_t)(b * NLQ + q0 + 1)) * NH + t];
    vs[t]         = vvec[t];
    actl[t]       = act[b * NLK + t];
    actl[t + 256] = act[b * NLK + t + 256];

    float acc00 = 0.f, acc01 = 0.f, acc10 = 0.f, acc11 = 0.f;
    const float* kpb = kp + (size_t)b * NLK * NH;

    for (int h0 = 0; h0 < NH; h0 += TH) {
        __syncthreads();   // protect kt (and on iter 0, qs/vs/actl)
        // stage kt[j][hh] = kp[j][h0+hh]: 512 rows x 16 h = 2048 float4s
        #pragma unroll
        for (int i = 0; i < 8; ++i) {
            const int lin = i * 256 + t;
            const int j   = lin >> 2;
            const int c4  = lin & 3;
            const float4 d = ((const float4*)(kpb + (size_t)j * NH + h0))[c4];
            kt[j][c4 * 4 + 0] = d.x;
            kt[j][c4 * 4 + 1] = d.y;
            kt[j][c4 * 4 + 2] = d.z;
            kt[j][c4 * 4 + 3] = d.w;
        }
        __syncthreads();
        #pragma unroll
        for (int hh = 0; hh < TH; ++hh) {
            const int h = h0 + hh;
            const float k0  = kt[t][hh];
            const float k1  = kt[t + 256][hh];
            const float q0v = qs[0][h];
            const float q1v = qs[1][h];
            const float vh  = vs[h];
            float e, r;
            e = __builtin_amdgcn_exp2f(q0v + k0); r = __builtin_amdgcn_rcpf(e + 1.0f); acc00 = fmaf(vh, r, acc00);
            e = __builtin_amdgcn_exp2f(q0v + k1); r = __builtin_amdgcn_rcpf(e + 1.0f); acc01 = fmaf(vh, r, acc01);
            e = __builtin_amdgcn_exp2f(q1v + k0); r = __builtin_amdgcn_rcpf(e + 1.0f); acc10 = fmaf(vh, r, acc10);
            e = __builtin_amdgcn_exp2f(q1v + k1); r = __builtin_amdgcn_rcpf(e + 1.0f); acc11 = fmaf(vh, r, acc11);
        }
    }

    // s = -2*acc (softmax-equivalent score); invalid columns -> -inf
    {
        const bool v0 = (t < na), v1 = (t + 256 < na);
        sc[0][t]       = v0 ? -2.0f * acc00 : -INFINITY;
        sc[0][t + 256] = v1 ? -2.0f * acc01 : -INFINITY;
        sc[1][t]       = v0 ? -2.0f * acc10 : -INFINITY;
        sc[1][t + 256] = v1 ? -2.0f * acc11 : -INFINITY;
    }
    __syncthreads();

    // softmax: wave w handles q-row w; scatter weights to out_w via act idx
    const int lane = t & 63, wave = t >> 6;
    if (wave < 2) {
        float* row = sc[wave];
        float vals[8];
        float m = -INFINITY;
        #pragma unroll
        for (int j8 = 0; j8 < 8; ++j8) {
            vals[j8] = row[lane + j8 * 64];
            m = fmaxf(m, vals[j8]);
        }
        #pragma unroll
        for (int s = 32; s >= 1; s >>= 1)
            m = fmaxf(m, __shfl_xor(m, s, 64));
        float sum = 0.0f;
        #pragma unroll
        for (int j8 = 0; j8 < 8; ++j8) {
            vals[j8] = __builtin_amdgcn_exp2f((vals[j8] - m) * LOG2E);
            sum += vals[j8];
        }
        #pragma unroll
        for (int s = 32; s >= 1; s >>= 1)
            sum += __shfl_xor(sum, s, 64);
        const float inv = __builtin_amdgcn_rcpf(sum);
        float* wout = out_w + (size_t)(b * NLQ + q0 + wave) * NLK;
        #pragma unroll
        for (int j8 = 0; j8 < 8; ++j8) {
            const int jj = lane + j8 * 64;
            const float w = vals[j8] * inv;
            row[jj] = w;
            if (jj < na) wout[actl[jj]] = w;   // masked stay memset-0
        }
    }
    __syncthreads();

    // output: out_o[b,q,h=t] = sum_{j<na} w[q][j] * value[b, act[j], t]
    float a0 = 0.f, a1 = 0.f;
    const float* vb = value + (size_t)b * NLK * NH + t;
    #pragma unroll 8
    for (int j = 0; j < na; ++j) {
        const float val = vb[(size_t)actl[j] * NH];
        a0 = fmaf(sc[0][j], val, a0);
        a1 = fmaf(sc[1][j], val, a1);
    }
    out_o[((size_t)(b * NLQ + q0)    ) * NH + t] = a0;
    out_o[((size_t)(b * NLQ + q0 + 1)) * NH + t] = a1;
}

// ---------------------------------------------------------------------------
extern "C" void kernel_launch(void* const* d_in, const int* in_sizes, int n_in,
                              void* d_out, int out_size, void* d_ws, size_t ws_size,
                              hipStream_t stream) {
    const float* query = (const float*)d_in[0];
    const float* key   = (const float*)d_in[1];
    const float* value = (const float*)d_in[2];
    const int*   mask  = (const int*)  d_in[3];
    const float* Wq    = (const float*)d_in[4];
    const float* bq    = (const float*)d_in[5];
    const float* Wk    = (const float*)d_in[6];
    const float* bk    = (const float*)d_in[7];
    const float* v     = (const float*)d_in[8];

    float* out_o = (float*)d_out;                 // [4,256,256]
    float* out_w = out_o + NB * NLQ * NH;         // [4,256,512]

    float* qp   = (float*)d_ws;                   // [4,256,256] scaled
    float* kp   = qp + NB * NLQ * NH;             // [4,512,256] scaled, compacted
    int*   act  = (int*)(kp + NB * NLK * NH);     // [4,512]
    int*   nact = act + NB * NLK;                 // [4]

    hipMemsetAsync(out_w, 0, (size_t)NB * NLQ * NLK * sizeof(float), stream);
    compact_kernel<<<NB, 64, 0, stream>>>(mask, act, nact);
    qproj_kernel<<<NB * NLQ / 4, 256, 0, stream>>>(query, Wq, bq, qp);
    kproj_kernel<<<NB * NLK / 4, 256, 0, stream>>>(key, Wk, bk, act, nact, kp);
    attn_kernel<<<NB * NLQ / 2, 256, 0, stream>>>(qp, kp, value, act, nact, v,
                                                  out_o, out_w);
}

// Round 3
// 143.418 us; speedup vs baseline: 1.7786x; 1.1091x over previous
//
#include <hip/hip_runtime.h>
#include <math.h>

#define NB  4
#define NLQ 256
#define NLK 512
#define NH  256

// scale folded into projections: exp2(SC*(q+k)) = exp(2*(q+k))
#define SCALE_2LOG2E 2.885390081777927f
#define LOG2E        1.4426950408889634f
#define PADK 20   // kt row stride in floats: 16B-aligned -> b128 LDS ops, full bank coverage

// ---------------------------------------------------------------------------
// Fused projection kernel: blocks [0,256) -> q rows (Wq,bq), [256,768) -> k
// rows (Wk,bk). Each block: 4 rows x 256 cols, thread t owns col h=t.
// Output pre-scaled by 2*log2(e).
// ---------------------------------------------------------------------------
__global__ __launch_bounds__(256) void prep_kernel(
    const float* __restrict__ query, const float* __restrict__ key,
    const float* __restrict__ Wq, const float* __restrict__ bq,
    const float* __restrict__ Wk, const float* __restrict__ bk,
    float* __restrict__ qp, float* __restrict__ kp)
{
    const int blk = blockIdx.x;
    const float *X, *W, *bias;
    float* out;
    int r0;
    if (blk < NB * NLQ / 4) {            // 256 blocks: 1024 q rows
        X = query; W = Wq; bias = bq; out = qp; r0 = blk * 4;
    } else {                              // 512 blocks: 2048 k rows
        X = key;   W = Wk; bias = bk; out = kp; r0 = (blk - NB * NLQ / 4) * 4;
    }

    __shared__ float xs[4][NH];
    const int t = threadIdx.x;
    ((float4*)&xs[0][0])[t] = ((const float4*)(X + (size_t)r0 * NH))[t];
    __syncthreads();

    float acc[4];
    const float bb = bias[t];
    #pragma unroll
    for (int r = 0; r < 4; ++r) acc[r] = bb;

    const float4* Wv = (const float4*)(W + (size_t)t * NH);
    #pragma unroll 4
    for (int c4 = 0; c4 < NH / 4; ++c4) {
        const float4 w = Wv[c4];
        #pragma unroll
        for (int r = 0; r < 4; ++r) {
            const float4 x = ((const float4*)xs[r])[c4];
            acc[r] = fmaf(x.x, w.x, acc[r]);
            acc[r] = fmaf(x.y, w.y, acc[r]);
            acc[r] = fmaf(x.z, w.z, acc[r]);
            acc[r] = fmaf(x.w, w.w, acc[r]);
        }
    }
    #pragma unroll
    for (int r = 0; r < 4; ++r)
        out[(size_t)(r0 + r) * NH + t] = acc[r] * SCALE_2LOG2E;
}

// ---------------------------------------------------------------------------
// Fused attn: self-compaction + scores + softmax + output + out_w zeroing.
// Block = 512 threads (8 waves), QT=2 q rows, grid = B*LQ/2 = 512.
// Thread t owns compact k-slot j=t. Waves with all slots >= na skip the
// score loop (staging-only). kt tile: pad-20 rows, b128 LDS ops.
// score(q,k) = const - 2*sum_h v[h]*rcp(exp2(q'+k')+1); const drops in
// softmax (shift invariance) -> bv unused.
// ---------------------------------------------------------------------------
__global__ __launch_bounds__(512) void attn_kernel(
    const float* __restrict__ qp, const float* __restrict__ kp,
    const float* __restrict__ value, const int* __restrict__ mask,
    const float* __restrict__ vvec,
    float* __restrict__ out_o, float* __restrict__ out_w)
{
    __shared__ float kt[NLK][PADK];       // 40 KB staged k-tile (16 h per pass)
    __shared__ float qs0[NH], qs1[NH], vsv[NH];
    __shared__ float sc0[NLK], sc1[NLK];
    __shared__ int   actl[NLK];
    __shared__ int   wcnt[8], wpre[9];

    const int blk  = blockIdx.x;
    const int b    = blk >> 7;            // 128 blocks per batch
    const int q0   = (blk & 127) * 2;
    const int t    = threadIdx.x;
    const int lane = t & 63;
    const int wave = t >> 6;

    // stage q rows (scaled) + v
    if (t < NH) {
        qs0[t] = qp[((size_t)(b * NLQ + q0)) * NH + t];
        vsv[t] = vvec[t];
    } else {
        const int h = t - NH;
        qs1[h] = qp[((size_t)(b * NLQ + q0 + 1)) * NH + h];
    }

    // ---- inline mask compaction (thread t owns original k=t) ----
    const int mk = mask[b * NLK + t];
    actl[t] = 0;                                        // tail init
    const unsigned long long bal = __ballot(mk != 0);
    const int rank = __popcll(bal & ((1ULL << lane) - 1ULL));
    if (lane == 0) wcnt[wave] = __popcll(bal);
    __syncthreads();
    if (t == 0) {
        int s = 0;
        #pragma unroll
        for (int w = 0; w < 8; ++w) { wpre[w] = s; s += wcnt[w]; }
        wpre[8] = s;
    }
    __syncthreads();
    const int na = wpre[8];
    if (mk) actl[wpre[wave] + rank] = t;
    // zero masked out_w slots (disjoint from softmax scatter)
    if (!mk) {
        out_w[((size_t)(b * NLQ + q0))     * NLK + t] = 0.0f;
        out_w[((size_t)(b * NLQ + q0 + 1)) * NLK + t] = 0.0f;
    }
    __syncthreads();

    // ---- score loop: 16-h tiles ----
    float acc0 = 0.0f, acc1 = 0.0f;
    const float* kpb = kp + (size_t)b * NLK * NH;
    const bool active_wave = (wave * 64 < na);

    for (int h0 = 0; h0 < NH; h0 += 16) {
        // stage kt[j][0..15] = kp[actl[j]][h0..h0+15]; 2048 float4 / 512 thr
        #pragma unroll
        for (int i = 0; i < 4; ++i) {
            const int lin = i * 512 + t;
            const int j   = lin >> 2;
            const int c4  = lin & 3;
            const int row = actl[j];
            const float4 d = *(const float4*)(kpb + (size_t)row * NH + h0 + c4 * 4);
            *(float4*)&kt[j][c4 * 4] = d;              // b128, stride-20 rows
        }
        __syncthreads();
        if (active_wave) {
            #pragma unroll
            for (int hh = 0; hh < 16; hh += 4) {
                const float4 kv = *(const float4*)&kt[t][hh];   // b128, conflict-free
                #pragma unroll
                for (int e = 0; e < 4; ++e) {
                    const int h = h0 + hh + e;
                    const float kx = (&kv.x)[e];
                    const float e0 = __builtin_amdgcn_exp2f(qs0[h] + kx);
                    const float e1 = __builtin_amdgcn_exp2f(qs1[h] + kx);
                    acc0 = fmaf(vsv[h], __builtin_amdgcn_rcpf(e0 + 1.0f), acc0);
                    acc1 = fmaf(vsv[h], __builtin_amdgcn_rcpf(e1 + 1.0f), acc1);
                }
            }
        }
        __syncthreads();
    }

    sc0[t] = (t < na) ? -2.0f * acc0 : -INFINITY;
    sc1[t] = (t < na) ? -2.0f * acc1 : -INFINITY;
    __syncthreads();

    // ---- softmax: wave 0 -> q row 0, wave 1 -> q row 1 ----
    if (wave < 2) {
        float* row = wave ? sc1 : sc0;
        float vals[8];
        float m = -INFINITY;
        #pragma unroll
        for (int j8 = 0; j8 < 8; ++j8) {
            vals[j8] = row[lane + j8 * 64];
            m = fmaxf(m, vals[j8]);
        }
        #pragma unroll
        for (int s = 32; s >= 1; s >>= 1)
            m = fmaxf(m, __shfl_xor(m, s, 64));
        float sum = 0.0f;
        #pragma unroll
        for (int j8 = 0; j8 < 8; ++j8) {
            vals[j8] = __builtin_amdgcn_exp2f((vals[j8] - m) * LOG2E);
            sum += vals[j8];
        }
        #pragma unroll
        for (int s = 32; s >= 1; s >>= 1)
            sum += __shfl_xor(sum, s, 64);
        const float inv = __builtin_amdgcn_rcpf(sum);
        float* wout = out_w + (size_t)(b * NLQ + q0 + wave) * NLK;
        #pragma unroll
        for (int j8 = 0; j8 < 8; ++j8) {
            const int jj = lane + j8 * 64;
            const float w = vals[j8] * inv;
            row[jj] = w;
            if (jj < na) wout[actl[jj]] = w;          // masked slots stay 0
        }
    }
    __syncthreads();

    // ---- output: threads t<256, h=t, both q rows ----
    if (t < NH) {
        float a0 = 0.0f, a1 = 0.0f;
        const float* vb = value + (size_t)b * NLK * NH + t;
        #pragma unroll 8
        for (int j = 0; j < na; ++j) {
            const float val = vb[(size_t)actl[j] * NH];
            a0 = fmaf(sc0[j], val, a0);
            a1 = fmaf(sc1[j], val, a1);
        }
        out_o[((size_t)(b * NLQ + q0))     * NH + t] = a0;
        out_o[((size_t)(b * NLQ + q0 + 1)) * NH + t] = a1;
    }
}

// ---------------------------------------------------------------------------
extern "C" void kernel_launch(void* const* d_in, const int* in_sizes, int n_in,
                              void* d_out, int out_size, void* d_ws, size_t ws_size,
                              hipStream_t stream) {
    const float* query = (const float*)d_in[0];
    const float* key   = (const float*)d_in[1];
    const float* value = (const float*)d_in[2];
    const int*   mask  = (const int*)  d_in[3];
    const float* Wq    = (const float*)d_in[4];
    const float* bq    = (const float*)d_in[5];
    const float* Wk    = (const float*)d_in[6];
    const float* bk    = (const float*)d_in[7];
    const float* v     = (const float*)d_in[8];
    // d_in[9] (bv) drops out of softmax -> unused

    float* out_o = (float*)d_out;                 // [4,256,256]
    float* out_w = out_o + NB * NLQ * NH;         // [4,256,512]

    float* qp = (float*)d_ws;                     // [4,256,256] scaled
    float* kp = qp + NB * NLQ * NH;               // [4,512,256] scaled

    prep_kernel<<<NB * NLQ / 4 + NB * NLK / 4, 256, 0, stream>>>(
        query, key, Wq, bq, Wk, bk, qp, kp);
    attn_kernel<<<NB * NLQ / 2, 512, 0, stream>>>(
        qp, kp, value, mask, v, out_o, out_w);
}

// Round 4
// 139.258 us; speedup vs baseline: 1.8318x; 1.0299x over previous
//
#include <hip/hip_runtime.h>
#include <math.h>

#define NB  4
#define NLQ 256
#define NLK 512
#define NH  256

// scale folded into projections: exp2(SC*(q+k)) = exp(2*(q+k))
#define SCALE_2LOG2E 2.885390081777927f
#define LOG2E        1.4426950408889634f

// ---------------------------------------------------------------------------
// Transpose Wq and Wk (256x256 each) -> Wt[c][h] = W[h][c].
// 32 blocks x 256 threads, 64x64 tiles via LDS. Tiny.
// ---------------------------------------------------------------------------
__global__ __launch_bounds__(256) void transpose_kernel(
    const float* __restrict__ Wq, const float* __restrict__ Wk,
    float* __restrict__ Wtq, float* __restrict__ Wtk)
{
    __shared__ float ts[64][65];
    const int blk  = blockIdx.x;
    const int m    = blk >> 4;               // 0: Wq, 1: Wk
    const int tile = blk & 15;
    const int h0 = (tile >> 2) * 64;
    const int c0 = (tile & 3) * 64;
    const float* W  = m ? Wk  : Wq;
    float*       Wt = m ? Wtk : Wtq;
    const int t  = threadIdx.x;
    const int lr = t >> 4, lc = t & 15;
    #pragma unroll
    for (int i = 0; i < 4; ++i) {
        const int r = lr + 16 * i;
        const float4 d = *(const float4*)(W + (size_t)(h0 + r) * NH + c0 + lc * 4);
        ts[r][lc * 4 + 0] = d.x;
        ts[r][lc * 4 + 1] = d.y;
        ts[r][lc * 4 + 2] = d.z;
        ts[r][lc * 4 + 3] = d.w;
    }
    __syncthreads();
    #pragma unroll
    for (int i = 0; i < 4; ++i) {
        const int c = lr + 16 * i;
        float4 d;
        d.x = ts[lc * 4 + 0][c];
        d.y = ts[lc * 4 + 1][c];
        d.z = ts[lc * 4 + 2][c];
        d.w = ts[lc * 4 + 3][c];
        *(float4*)(Wt + (size_t)(c0 + c) * NH + h0 + lc * 4) = d;
    }
}

// ---------------------------------------------------------------------------
// Fused projections using transposed weights.
// Block = 256 threads = 4 waves; 8 rows/block (wave w owns rows r0+2w..+1).
// Thread lane owns h-quad (t&63)*4 -> Wt reads are coalesced b128 (1KB/wave).
// X values are wave-uniform loads (single line, L1-hit).
// Output pre-scaled by 2*log2(e).
// ---------------------------------------------------------------------------
__global__ __launch_bounds__(256) void prep_kernel(
    const float* __restrict__ query, const float* __restrict__ key,
    const float* __restrict__ Wtq, const float* __restrict__ bq,
    const float* __restrict__ Wtk, const float* __restrict__ bk,
    float* __restrict__ qp, float* __restrict__ kp)
{
    const int blk = blockIdx.x;
    const float *X, *Wt, *bias;
    float* out;
    int r0;
    if (blk < NB * NLQ / 8) {                 // 128 blocks: 1024 q rows
        X = query; Wt = Wtq; bias = bq; out = qp; r0 = blk * 8;
    } else {                                  // 256 blocks: 2048 k rows
        X = key;   Wt = Wtk; bias = bk; out = kp; r0 = (blk - NB * NLQ / 8) * 8;
    }
    const int t    = threadIdx.x;
    const int wave = t >> 6;
    const int hq   = (t & 63) * 4;

    const float* xr0 = X + (size_t)(r0 + 2 * wave) * NH;
    const float* xr1 = xr0 + NH;

    float4 acc0 = {0.f, 0.f, 0.f, 0.f};
    float4 acc1 = {0.f, 0.f, 0.f, 0.f};

    #pragma unroll 2
    for (int c = 0; c < NH; c += 4) {
        const float4 xa = *(const float4*)(xr0 + c);   // wave-uniform
        const float4 xb = *(const float4*)(xr1 + c);   // wave-uniform
        #pragma unroll
        for (int e = 0; e < 4; ++e) {
            const float4 w = *(const float4*)(Wt + (size_t)(c + e) * NH + hq); // coalesced
            const float xae = (&xa.x)[e];
            const float xbe = (&xb.x)[e];
            acc0.x = fmaf(xae, w.x, acc0.x);
            acc0.y = fmaf(xae, w.y, acc0.y);
            acc0.z = fmaf(xae, w.z, acc0.z);
            acc0.w = fmaf(xae, w.w, acc0.w);
            acc1.x = fmaf(xbe, w.x, acc1.x);
            acc1.y = fmaf(xbe, w.y, acc1.y);
            acc1.z = fmaf(xbe, w.z, acc1.z);
            acc1.w = fmaf(xbe, w.w, acc1.w);
        }
    }

    const float4 bb = *(const float4*)(bias + hq);
    float4 o0, o1;
    o0.x = (acc0.x + bb.x) * SCALE_2LOG2E;
    o0.y = (acc0.y + bb.y) * SCALE_2LOG2E;
    o0.z = (acc0.z + bb.z) * SCALE_2LOG2E;
    o0.w = (acc0.w + bb.w) * SCALE_2LOG2E;
    o1.x = (acc1.x + bb.x) * SCALE_2LOG2E;
    o1.y = (acc1.y + bb.y) * SCALE_2LOG2E;
    o1.z = (acc1.z + bb.z) * SCALE_2LOG2E;
    o1.w = (acc1.w + bb.w) * SCALE_2LOG2E;
    *(float4*)(out + (size_t)(r0 + 2 * wave)     * NH + hq) = o0;
    *(float4*)(out + (size_t)(r0 + 2 * wave + 1) * NH + hq) = o1;
}

// ---------------------------------------------------------------------------
// Fused attn: compaction + scores + softmax + output. Block = 256 threads
// (4 waves), 2 q rows, grid = 512. Thread t owns compact slot t (and t+256
// in the rare na>256 overflow pass). Score loop: per-lane kp-row streaming
// (float4, L1 line reuse), q/v via wave-uniform loads -> scalar operands.
// NO LDS and NO barriers inside the score loop.
// score'(q,k) = -2*sum_h v[h]*rcp(exp2(q'+k')+1)   (shift-invariant form)
// ---------------------------------------------------------------------------
__global__ __launch_bounds__(256) void attn_kernel(
    const float* __restrict__ qp, const float* __restrict__ kp,
    const float* __restrict__ value, const int* __restrict__ mask,
    const float* __restrict__ vvec,
    float* __restrict__ out_o, float* __restrict__ out_w)
{
    __shared__ float sc0[NLK], sc1[NLK];
    __shared__ int   actl[NLK];
    __shared__ int   wcnt[8];
    __shared__ int   wpre[9];

    const int blk  = blockIdx.x;
    const int b    = blk >> 7;               // 128 blocks per batch
    const int q0   = (blk & 127) * 2;
    const int t    = threadIdx.x;            // 0..255
    const int lane = t & 63;
    const int wave = t >> 6;                 // 0..3

    // ---- compaction: 512 mask bits, 2 per thread ----
    const int k1 = t, k2 = t + 256;
    const int m1 = mask[b * NLK + k1];
    const int m2 = mask[b * NLK + k2];
    actl[k1] = 0;
    actl[k2] = 0;
    const unsigned long long below = (1ULL << lane) - 1ULL;
    const unsigned long long bal1 = __ballot(m1 != 0);
    const unsigned long long bal2 = __ballot(m2 != 0);
    const int r1 = __popcll(bal1 & below);
    const int r2 = __popcll(bal2 & below);
    if (lane == 0) { wcnt[wave] = __popcll(bal1); wcnt[4 + wave] = __popcll(bal2); }
    __syncthreads();
    if (t == 0) {
        int s = 0;
        #pragma unroll
        for (int w = 0; w < 8; ++w) { wpre[w] = s; s += wcnt[w]; }
        wpre[8] = s;
    }
    __syncthreads();
    const int na = wpre[8];
    if (m1) actl[wpre[wave]     + r1] = k1;
    if (m2) actl[wpre[4 + wave] + r2] = k2;
    // zero masked out_w slots (active slots written by softmax scatter)
    float* w0row = out_w + (size_t)(b * NLQ + q0) * NLK;
    float* w1row = w0row + NLK;
    if (!m1) { w0row[k1] = 0.f; w1row[k1] = 0.f; }
    if (!m2) { w0row[k2] = 0.f; w1row[k2] = 0.f; }
    __syncthreads();

    // ---- score pass 1: slot t (uniform flow; tail lanes compute on row 0) ----
    const float* qr0 = qp + (size_t)(b * NLQ + q0) * NH;   // uniform
    const float* qr1 = qr0 + NH;                           // uniform
    const float* kpb = kp + (size_t)b * NLK * NH;

    {
        const float* kr = kpb + (size_t)actl[t] * NH;
        float a0 = 0.f, a1 = 0.f;
        #pragma unroll 2
        for (int c = 0; c < NH; c += 4) {
            const float4 kx = *(const float4*)(kr + c);    // per-lane stream
            const float4 qa = *(const float4*)(qr0 + c);   // uniform -> s_load
            const float4 qb = *(const float4*)(qr1 + c);   // uniform -> s_load
            const float4 vv = *(const float4*)(vvec + c);  // uniform -> s_load
            #pragma unroll
            for (int e = 0; e < 4; ++e) {
                const float kk = (&kx.x)[e];
                const float e0 = __builtin_amdgcn_exp2f((&qa.x)[e] + kk);
                const float e1 = __builtin_amdgcn_exp2f((&qb.x)[e] + kk);
                a0 = fmaf((&vv.x)[e], __builtin_amdgcn_rcpf(e0 + 1.f), a0);
                a1 = fmaf((&vv.x)[e], __builtin_amdgcn_rcpf(e1 + 1.f), a1);
            }
        }
        sc0[t] = (t < na) ? -2.f * a0 : -INFINITY;
        sc1[t] = (t < na) ? -2.f * a1 : -INFINITY;
    }

    // ---- score pass 2: overflow slots (na > 256), divergent but rare ----
    {
        const int j2 = t + 256;
        float a0 = 0.f, a1 = 0.f;
        if (j2 < na) {
            const float* kr = kpb + (size_t)actl[j2] * NH;
            #pragma unroll 2
            for (int c = 0; c < NH; c += 4) {
                const float4 kx = *(const float4*)(kr + c);
                const float4 qa = *(const float4*)(qr0 + c);
                const float4 qb = *(const float4*)(qr1 + c);
                const float4 vv = *(const float4*)(vvec + c);
                #pragma unroll
                for (int e = 0; e < 4; ++e) {
                    const float kk = (&kx.x)[e];
                    const float e0 = __builtin_amdgcn_exp2f((&qa.x)[e] + kk);
                    const float e1 = __builtin_amdgcn_exp2f((&qb.x)[e] + kk);
                    a0 = fmaf((&vv.x)[e], __builtin_amdgcn_rcpf(e0 + 1.f), a0);
                    a1 = fmaf((&vv.x)[e], __builtin_amdgcn_rcpf(e1 + 1.f), a1);
                }
            }
        }
        sc0[j2] = (j2 < na) ? -2.f * a0 : -INFINITY;
        sc1[j2] = (j2 < na) ? -2.f * a1 : -INFINITY;
    }
    __syncthreads();

    // ---- softmax: wave 0 -> q row 0, wave 1 -> q row 1 (512 slots, 8/lane) --
    if (wave < 2) {
        float* row = wave ? sc1 : sc0;
        float vals[8];
        float m = -INFINITY;
        #pragma unroll
        for (int j8 = 0; j8 < 8; ++j8) {
            vals[j8] = row[lane + j8 * 64];
            m = fmaxf(m, vals[j8]);
        }
        #pragma unroll
        for (int s = 32; s >= 1; s >>= 1)
            m = fmaxf(m, __shfl_xor(m, s, 64));
        float sum = 0.0f;
        #pragma unroll
        for (int j8 = 0; j8 < 8; ++j8) {
            vals[j8] = __builtin_amdgcn_exp2f((vals[j8] - m) * LOG2E);
            sum += vals[j8];
        }
        #pragma unroll
        for (int s = 32; s >= 1; s >>= 1)
            sum += __shfl_xor(sum, s, 64);
        const float inv = __builtin_amdgcn_rcpf(sum);
        float* wout = out_w + (size_t)(b * NLQ + q0 + wave) * NLK;
        #pragma unroll
        for (int j8 = 0; j8 < 8; ++j8) {
            const int jj = lane + j8 * 64;
            const float w = vals[j8] * inv;
            row[jj] = w;                      // 0 for jj >= na
            if (jj < na) wout[actl[jj]] = w;  // masked slots stay 0
        }
    }
    __syncthreads();

    // ---- output: thread t = column h, both q rows; weights are 0 past na ---
    {
        const float* vb = value + (size_t)b * NLK * NH + t;
        float o0 = 0.f, o1 = 0.f;
        const int n4 = (na + 3) >> 2;
        for (int j4 = 0; j4 < n4; ++j4) {
            const float4 w0 = ((const float4*)sc0)[j4];
            const float4 w1 = ((const float4*)sc1)[j4];
            const int4   aj = ((const int4*)actl)[j4];
            const float v0 = vb[(size_t)aj.x * NH];
            const float v1 = vb[(size_t)aj.y * NH];
            const float v2 = vb[(size_t)aj.z * NH];
            const float v3 = vb[(size_t)aj.w * NH];
            o0 = fmaf(w0.x, v0, o0); o1 = fmaf(w1.x, v0, o1);
            o0 = fmaf(w0.y, v1, o0); o1 = fmaf(w1.y, v1, o1);
            o0 = fmaf(w0.z, v2, o0); o1 = fmaf(w1.z, v2, o1);
            o0 = fmaf(w0.w, v3, o0); o1 = fmaf(w1.w, v3, o1);
        }
        out_o[(size_t)(b * NLQ + q0)     * NH + t] = o0;
        out_o[(size_t)(b * NLQ + q0 + 1) * NH + t] = o1;
    }
}

// ---------------------------------------------------------------------------
extern "C" void kernel_launch(void* const* d_in, const int* in_sizes, int n_in,
                              void* d_out, int out_size, void* d_ws, size_t ws_size,
                              hipStream_t stream) {
    const float* query = (const float*)d_in[0];
    const float* key   = (const float*)d_in[1];
    const float* value = (const float*)d_in[2];
    const int*   mask  = (const int*)  d_in[3];
    const float* Wq    = (const float*)d_in[4];
    const float* bq    = (const float*)d_in[5];
    const float* Wk    = (const float*)d_in[6];
    const float* bk    = (const float*)d_in[7];
    const float* v     = (const float*)d_in[8];
    // d_in[9] (bv) drops out of softmax -> unused

    float* out_o = (float*)d_out;                     // [4,256,256]
    float* out_w = out_o + NB * NLQ * NH;             // [4,256,512]

    float* qp = (float*)d_ws;                         // [4,256,256] scaled
    float* kp = qp + NB * NLQ * NH;                   // [4,512,256] scaled

    const size_t base = (size_t)(NB * NLQ * NH + NB * NLK * NH);
    float* wtq;
    float* wtk;
    if (ws_size >= (base + 2 * NH * NH) * sizeof(float)) {
        wtq = (float*)d_ws + base;                    // workspace tail
    } else {
        // park W^T in the out_w tail; attn_kernel fully overwrites out_w later
        wtq = out_w + (size_t)NB * NLQ * NLK - 2 * NH * NH;
    }
    wtk = wtq + NH * NH;

    transpose_kernel<<<32, 256, 0, stream>>>(Wq, Wk, wtq, wtk);
    prep_kernel<<<NB * NLQ / 8 + NB * NLK / 8, 256, 0, stream>>>(
        query, key, wtq, bq, wtk, bk, qp, kp);
    attn_kernel<<<NB * NLQ / 2, 256, 0, stream>>>(
        qp, kp, value, mask, v, out_o, out_w);
}

// Round 5
// 139.114 us; speedup vs baseline: 1.8337x; 1.0010x over previous
//
#include <hip/hip_runtime.h>
#include <math.h>

#define NB  4
#define NLQ 256
#define NLK 512
#define NH  256

// scale folded into projections: exp2(SC*(q+k)) = exp(2*(q+k))
#define SCALE_2LOG2E 2.885390081777927f
#define LOG2E        1.4426950408889634f

// ---------------------------------------------------------------------------
// Transpose Wq and Wk (256x256 each) -> Wt[c][h] = W[h][c].
// 32 blocks x 256 threads, 64x64 tiles via LDS.
// ---------------------------------------------------------------------------
__global__ __launch_bounds__(256) void transpose_kernel(
    const float* __restrict__ Wq, const float* __restrict__ Wk,
    float* __restrict__ Wtq, float* __restrict__ Wtk)
{
    __shared__ float ts[64][65];
    const int blk  = blockIdx.x;
    const int m    = blk >> 4;               // 0: Wq, 1: Wk
    const int tile = blk & 15;
    const int h0 = (tile >> 2) * 64;
    const int c0 = (tile & 3) * 64;
    const float* W  = m ? Wk  : Wq;
    float*       Wt = m ? Wtk : Wtq;
    const int t  = threadIdx.x;
    const int lr = t >> 4, lc = t & 15;
    #pragma unroll
    for (int i = 0; i < 4; ++i) {
        const int r = lr + 16 * i;
        const float4 d = *(const float4*)(W + (size_t)(h0 + r) * NH + c0 + lc * 4);
        ts[r][lc * 4 + 0] = d.x;
        ts[r][lc * 4 + 1] = d.y;
        ts[r][lc * 4 + 2] = d.z;
        ts[r][lc * 4 + 3] = d.w;
    }
    __syncthreads();
    #pragma unroll
    for (int i = 0; i < 4; ++i) {
        const int c = lr + 16 * i;
        float4 d;
        d.x = ts[lc * 4 + 0][c];
        d.y = ts[lc * 4 + 1][c];
        d.z = ts[lc * 4 + 2][c];
        d.w = ts[lc * 4 + 3][c];
        *(float4*)(Wt + (size_t)(c0 + c) * NH + h0 + lc * 4) = d;
    }
}

// ---------------------------------------------------------------------------
// Fused projections, c-split across waves.
// 768 blocks x 256 threads; 4 rows/block. All 4 waves process the SAME 4
// rows over disjoint c-ranges (wave w: c in [64w,64w+64)); lane owns h-quad
// lane*4 -> Wt reads are coalesced b128 (1KB/wave/c). X rows staged in LDS
// once (broadcast reads). Partials combined via LDS. Output pre-scaled.
// ---------------------------------------------------------------------------
__global__ __launch_bounds__(256) void prep_kernel(
    const float* __restrict__ query, const float* __restrict__ key,
    const float* __restrict__ Wtq, const float* __restrict__ bq,
    const float* __restrict__ Wtk, const float* __restrict__ bk,
    float* __restrict__ qp, float* __restrict__ kp)
{
    const int blk = blockIdx.x;
    const float *X, *Wt, *bias;
    float* out;
    int r0;
    if (blk < NB * NLQ / 4) {                 // 256 blocks: 1024 q rows
        X = query; Wt = Wtq; bias = bq; out = qp; r0 = blk * 4;
    } else {                                  // 512 blocks: 2048 k rows
        X = key;   Wt = Wtk; bias = bk; out = kp; r0 = (blk - NB * NLQ / 4) * 4;
    }
    const int t    = threadIdx.x;
    const int wave = t >> 6;
    const int lane = t & 63;

    __shared__ float  xs[4][NH];              // 4 staged input rows
    __shared__ float4 ps[4][4][64];           // [wave][row][lane] partials

    ((float4*)&xs[0][0])[t] = ((const float4*)(X + (size_t)r0 * NH))[t];
    __syncthreads();

    float4 acc[4];
    #pragma unroll
    for (int r = 0; r < 4; ++r) acc[r] = (float4){0.f, 0.f, 0.f, 0.f};

    const int cbase = wave * 64;
    #pragma unroll 4
    for (int cc = 0; cc < 64; ++cc) {
        const int c = cbase + cc;
        const float4 w = *(const float4*)(Wt + (size_t)c * NH + lane * 4);
        #pragma unroll
        for (int r = 0; r < 4; ++r) {
            const float xv = xs[r][c];        // LDS broadcast
            acc[r].x = fmaf(xv, w.x, acc[r].x);
            acc[r].y = fmaf(xv, w.y, acc[r].y);
            acc[r].z = fmaf(xv, w.z, acc[r].z);
            acc[r].w = fmaf(xv, w.w, acc[r].w);
        }
    }
    #pragma unroll
    for (int r = 0; r < 4; ++r) ps[wave][r][lane] = acc[r];
    __syncthreads();

    // combine: thread t -> row r = t>>6, lane quad l = t&63
    {
        const int r = wave, l = lane;
        const float4 p0 = ps[0][r][l], p1 = ps[1][r][l];
        const float4 p2 = ps[2][r][l], p3 = ps[3][r][l];
        const float4 bb = *(const float4*)(bias + l * 4);
        float4 o;
        o.x = (p0.x + p1.x + p2.x + p3.x + bb.x) * SCALE_2LOG2E;
        o.y = (p0.y + p1.y + p2.y + p3.y + bb.y) * SCALE_2LOG2E;
        o.z = (p0.z + p1.z + p2.z + p3.z + bb.z) * SCALE_2LOG2E;
        o.w = (p0.w + p1.w + p2.w + p3.w + bb.w) * SCALE_2LOG2E;
        *(float4*)(out + (size_t)(r0 + r) * NH + l * 4) = o;
    }
}

// ---------------------------------------------------------------------------
// Fused attn: compaction + scores + softmax + output. Block = 512 threads
// (8 waves), 2 q rows, grid = 512 -> 16 waves/CU. h-split: thread t owns
// compact slot j=t&255 and h-half (t>>8)*128; partials combined via LDS.
// Score loop: per-lane kp-row stream, q/v wave-uniform loads; no LDS, no
// barriers inside. score'(q,k) = -2*sum_h v[h]*rcp(exp2(q'+k')+1).
// ---------------------------------------------------------------------------
__global__ __launch_bounds__(512) void attn_kernel(
    const float* __restrict__ qp, const float* __restrict__ kp,
    const float* __restrict__ value, const int* __restrict__ mask,
    const float* __restrict__ vvec,
    float* __restrict__ out_o, float* __restrict__ out_w)
{
    __shared__ float sc0[NLK], sc1[NLK];
    __shared__ int   actl[NLK];
    __shared__ float ph0[512], ph1[512];
    __shared__ int   wcnt[8];
    __shared__ int   wpre[9];

    const int blk  = blockIdx.x;
    const int b    = blk >> 7;               // 128 blocks per batch
    const int q0   = (blk & 127) * 2;
    const int t    = threadIdx.x;            // 0..511
    const int lane = t & 63;
    const int wave = t >> 6;                 // 0..7

    // ---- compaction: thread t owns mask bit t ----
    const int mk = mask[b * NLK + t];
    actl[t] = 0;
    const unsigned long long bal = __ballot(mk != 0);
    const int rank = __popcll(bal & ((1ULL << lane) - 1ULL));
    if (lane == 0) wcnt[wave] = __popcll(bal);
    __syncthreads();
    if (t == 0) {
        int s = 0;
        #pragma unroll
        for (int w = 0; w < 8; ++w) { wpre[w] = s; s += wcnt[w]; }
        wpre[8] = s;
    }
    __syncthreads();
    const int na = wpre[8];
    if (mk) actl[wpre[wave] + rank] = t;
    // zero masked out_w slots (active slots written by softmax scatter)
    float* w0row = out_w + (size_t)(b * NLQ + q0) * NLK;
    float* w1row = w0row + NLK;
    if (!mk) { w0row[t] = 0.f; w1row[t] = 0.f; }
    __syncthreads();

    const int  j1    = t & 255;
    const int  hbase = (t >> 8) * 128;       // wave-uniform
    const float* qr0 = qp + (size_t)(b * NLQ + q0) * NH + hbase;
    const float* qr1 = qr0 + NH;
    const float* vvh = vvec + hbase;
    const float* kpb = kp + (size_t)b * NLK * NH;

    // ---- score pass 1: slots [0,256) ----
    {
        const float* kr = kpb + (size_t)actl[j1] * NH + hbase;
        float a0 = 0.f, a1 = 0.f;
        #pragma unroll 4
        for (int c = 0; c < 128; c += 4) {
            const float4 kx = *(const float4*)(kr + c);    // per-lane stream
            const float4 qa = *(const float4*)(qr0 + c);   // wave-uniform
            const float4 qb = *(const float4*)(qr1 + c);   // wave-uniform
            const float4 vv = *(const float4*)(vvh + c);   // wave-uniform
            #pragma unroll
            for (int e = 0; e < 4; ++e) {
                const float kk = (&kx.x)[e];
                const float e0 = __builtin_amdgcn_exp2f((&qa.x)[e] + kk);
                const float e1 = __builtin_amdgcn_exp2f((&qb.x)[e] + kk);
                a0 = fmaf((&vv.x)[e], __builtin_amdgcn_rcpf(e0 + 1.f), a0);
                a1 = fmaf((&vv.x)[e], __builtin_amdgcn_rcpf(e1 + 1.f), a1);
            }
        }
        ph0[t] = a0;
        ph1[t] = a1;
    }
    __syncthreads();
    if (t < 256) {
        const float s0 = ph0[t] + ph0[t + 256];
        const float s1 = ph1[t] + ph1[t + 256];
        sc0[t] = (t < na) ? -2.f * s0 : -INFINITY;
        sc1[t] = (t < na) ? -2.f * s1 : -INFINITY;
    }

    // ---- score pass 2: overflow slots [256, na), rare & cheap ----
    {
        const int j2 = 256 + j1;
        float a0 = 0.f, a1 = 0.f;
        if (j2 < na) {
            const float* kr = kpb + (size_t)actl[j2] * NH + hbase;
            #pragma unroll 4
            for (int c = 0; c < 128; c += 4) {
                const float4 kx = *(const float4*)(kr + c);
                const float4 qa = *(const float4*)(qr0 + c);
                const float4 qb = *(const float4*)(qr1 + c);
                const float4 vv = *(const float4*)(vvh + c);
                #pragma unroll
                for (int e = 0; e < 4; ++e) {
                    const float kk = (&kx.x)[e];
                    const float e0 = __builtin_amdgcn_exp2f((&qa.x)[e] + kk);
                    const float e1 = __builtin_amdgcn_exp2f((&qb.x)[e] + kk);
                    a0 = fmaf((&vv.x)[e], __builtin_amdgcn_rcpf(e0 + 1.f), a0);
                    a1 = fmaf((&vv.x)[e], __builtin_amdgcn_rcpf(e1 + 1.f), a1);
                }
            }
        }
        __syncthreads();                 // ph reuse
        ph0[t] = a0;
        ph1[t] = a1;
    }
    __syncthreads();
    if (t < 256) {
        const int j2 = t + 256;
        const float s0 = ph0[t] + ph0[t + 256];
        const float s1 = ph1[t] + ph1[t + 256];
        sc0[j2] = (j2 < na) ? -2.f * s0 : -INFINITY;
        sc1[j2] = (j2 < na) ? -2.f * s1 : -INFINITY;
    }
    __syncthreads();

    // ---- softmax: wave 0 -> q row 0, wave 1 -> q row 1 (512 slots) ----
    if (wave < 2) {
        float* row = wave ? sc1 : sc0;
        float vals[8];
        float m = -INFINITY;
        #pragma unroll
        for (int j8 = 0; j8 < 8; ++j8) {
            vals[j8] = row[lane + j8 * 64];
            m = fmaxf(m, vals[j8]);
        }
        #pragma unroll
        for (int s = 32; s >= 1; s >>= 1)
            m = fmaxf(m, __shfl_xor(m, s, 64));
        float sum = 0.0f;
        #pragma unroll
        for (int j8 = 0; j8 < 8; ++j8) {
            vals[j8] = __builtin_amdgcn_exp2f((vals[j8] - m) * LOG2E);
            sum += vals[j8];
        }
        #pragma unroll
        for (int s = 32; s >= 1; s >>= 1)
            sum += __shfl_xor(sum, s, 64);
        const float inv = __builtin_amdgcn_rcpf(sum);
        float* wout = out_w + (size_t)(b * NLQ + q0 + wave) * NLK;
        #pragma unroll
        for (int j8 = 0; j8 < 8; ++j8) {
            const int jj = lane + j8 * 64;
            const float w = vals[j8] * inv;
            row[jj] = w;                      // 0 for jj >= na
            if (jj < na) wout[actl[jj]] = w;  // masked slots stay 0
        }
    }
    __syncthreads();

    // ---- output: thread t -> h = t&255, j-half (t>>8); LDS combine ----
    {
        const int h     = t & 255;
        const int j4b   = (t >> 8) * 64;       // wave-uniform float4 index
        const float* vb = value + (size_t)b * NLK * NH + h;
        float o0 = 0.f, o1 = 0.f;
        #pragma unroll 4
        for (int i = 0; i < 64; ++i) {
            const int j4 = j4b + i;
            const float4 w0 = ((const float4*)sc0)[j4];   // LDS broadcast
            const float4 w1 = ((const float4*)sc1)[j4];
            const int4   aj = ((const int4*)actl)[j4];
            const float v0 = vb[(size_t)aj.x * NH];
            const float v1 = vb[(size_t)aj.y * NH];
            const float v2 = vb[(size_t)aj.z * NH];
            const float v3 = vb[(size_t)aj.w * NH];
            o0 = fmaf(w0.x, v0, o0); o1 = fmaf(w1.x, v0, o1);
            o0 = fmaf(w0.y, v1, o0); o1 = fmaf(w1.y, v1, o1);
            o0 = fmaf(w0.z, v2, o0); o1 = fmaf(w1.z, v2, o1);
            o0 = fmaf(w0.w, v3, o0); o1 = fmaf(w1.w, v3, o1);
        }
        ph0[t] = o0;
        ph1[t] = o1;
    }
    __syncthreads();
    if (t < 256) {
        out_o[(size_t)(b * NLQ + q0)     * NH + t] = ph0[t] + ph0[t + 256];
        out_o[(size_t)(b * NLQ + q0 + 1) * NH + t] = ph1[t] + ph1[t + 256];
    }
}

// ---------------------------------------------------------------------------
extern "C" void kernel_launch(void* const* d_in, const int* in_sizes, int n_in,
                              void* d_out, int out_size, void* d_ws, size_t ws_size,
                              hipStream_t stream) {
    const float* query = (const float*)d_in[0];
    const float* key   = (const float*)d_in[1];
    const float* value = (const float*)d_in[2];
    const int*   mask  = (const int*)  d_in[3];
    const float* Wq    = (const float*)d_in[4];
    const float* bq    = (const float*)d_in[5];
    const float* Wk    = (const float*)d_in[6];
    const float* bk    = (const float*)d_in[7];
    const float* v     = (const float*)d_in[8];
    // d_in[9] (bv) drops out of softmax -> unused

    float* out_o = (float*)d_out;                     // [4,256,256]
    float* out_w = out_o + NB * NLQ * NH;             // [4,256,512]

    float* qp = (float*)d_ws;                         // [4,256,256] scaled
    float* kp = qp + NB * NLQ * NH;                   // [4,512,256] scaled

    const size_t base = (size_t)(NB * NLQ * NH + NB * NLK * NH);
    float* wtq;
    float* wtk;
    if (ws_size >= (base + 2 * NH * NH) * sizeof(float)) {
        wtq = (float*)d_ws + base;                    // workspace tail
    } else {
        // park W^T in the out_w tail; attn_kernel fully overwrites out_w later
        wtq = out_w + (size_t)NB * NLQ * NLK - 2 * NH * NH;
    }
    wtk = wtq + NH * NH;

    transpose_kernel<<<32, 256, 0, stream>>>(Wq, Wk, wtq, wtk);
    prep_kernel<<<NB * NLQ / 4 + NB * NLK / 4, 256, 0, stream>>>(
        query, key, wtq, bq, wtk, bk, qp, kp);
    attn_kernel<<<NB * NLQ / 2, 512, 0, stream>>>(
        qp, kp, value, mask, v, out_o, out_w);
}

// Round 6
// 130.155 us; speedup vs baseline: 1.9599x; 1.0688x over previous
//
#include <hip/hip_runtime.h>
#include <math.h>

#define NB  4
#define NLQ 256
#define NLK 512
#define NH  256

// scale folded into projections: exp2(SC*(q+k)) = exp(2*(q+k))
#define SCALE_2LOG2E 2.885390081777927f
#define LOG2E        1.4426950408889634f

// ---------------------------------------------------------------------------
// Setup: W transposes (blocks 0..31) + per-batch mask compaction (32..35).
// ---------------------------------------------------------------------------
__global__ __launch_bounds__(256) void setup_kernel(
    const float* __restrict__ Wq, const float* __restrict__ Wk,
    const int* __restrict__ mask,
    float* __restrict__ Wtq, float* __restrict__ Wtk,
    int* __restrict__ act, int* __restrict__ nact)
{
    const int blk = blockIdx.x;
    const int t   = threadIdx.x;

    if (blk < 32) {
        // ---- transpose one 64x64 tile of Wq/Wk into Wtq/Wtk ----
        __shared__ float ts[64][65];
        const int m    = blk >> 4;               // 0: Wq, 1: Wk
        const int tile = blk & 15;
        const int h0 = (tile >> 2) * 64;
        const int c0 = (tile & 3) * 64;
        const float* W  = m ? Wk  : Wq;
        float*       Wt = m ? Wtk : Wtq;
        const int lr = t >> 4, lc = t & 15;
        #pragma unroll
        for (int i = 0; i < 4; ++i) {
            const int r = lr + 16 * i;
            const float4 d = *(const float4*)(W + (size_t)(h0 + r) * NH + c0 + lc * 4);
            ts[r][lc * 4 + 0] = d.x;
            ts[r][lc * 4 + 1] = d.y;
            ts[r][lc * 4 + 2] = d.z;
            ts[r][lc * 4 + 3] = d.w;
        }
        __syncthreads();
        #pragma unroll
        for (int i = 0; i < 4; ++i) {
            const int c = lr + 16 * i;
            float4 d;
            d.x = ts[lc * 4 + 0][c];
            d.y = ts[lc * 4 + 1][c];
            d.z = ts[lc * 4 + 2][c];
            d.w = ts[lc * 4 + 3][c];
            *(float4*)(Wt + (size_t)(c0 + c) * NH + h0 + lc * 4) = d;
        }
    } else if (blk < 32 + NB) {
        // ---- mask compaction for batch b ----
        const int b = blk - 32;
        __shared__ int wcnt[8], wpre[9];
        const int lane = t & 63, wave = t >> 6;
        const int k1 = t, k2 = t + 256;
        const int m1 = mask[b * NLK + k1];
        const int m2 = mask[b * NLK + k2];
        const unsigned long long below = (1ULL << lane) - 1ULL;
        const unsigned long long bal1 = __ballot(m1 != 0);
        const unsigned long long bal2 = __ballot(m2 != 0);
        const int r1 = __popcll(bal1 & below);
        const int r2 = __popcll(bal2 & below);
        if (lane == 0) { wcnt[wave] = __popcll(bal1); wcnt[4 + wave] = __popcll(bal2); }
        __syncthreads();
        if (t == 0) {
            int s = 0;
            #pragma unroll
            for (int w = 0; w < 8; ++w) { wpre[w] = s; s += wcnt[w]; }
            wpre[8] = s;
        }
        __syncthreads();
        const int na = wpre[8];
        if (m1) act[b * NLK + wpre[wave]     + r1] = k1;
        if (m2) act[b * NLK + wpre[4 + wave] + r2] = k2;
        if (k1 >= na) act[b * NLK + k1] = 0;     // safe tail for padded reads
        if (k2 >= na) act[b * NLK + k2] = 0;
        if (t == 0) nact[b] = na;
    }
}

// ---------------------------------------------------------------------------
// Fused projections (c-split across waves, coalesced Wt loads).
// Blocks 0..255: q rows (4/block) -> qp[b][lq][h] (scaled).
// Blocks 256..767: compact k slots (4/block, gathered via act) ->
//   kp_ct[b][h][j] compact-TRANSPOSED (scaled), so attn reads coalesce.
// ---------------------------------------------------------------------------
__global__ __launch_bounds__(256) void prep_kernel(
    const float* __restrict__ query, const float* __restrict__ key,
    const float* __restrict__ Wtq, const float* __restrict__ bq,
    const float* __restrict__ Wtk, const float* __restrict__ bk,
    const int* __restrict__ act, const int* __restrict__ nact,
    float* __restrict__ qp, float* __restrict__ kp_ct)
{
    const int blk  = blockIdx.x;
    const int t    = threadIdx.x;
    const int wave = t >> 6;
    const int lane = t & 63;

    __shared__ float  xs[4][NH];
    __shared__ float4 ps[4][4][64];
    __shared__ int    ridx[4];

    const float *Wt, *bias;
    int b = 0, j0 = 0, r0 = 0, na = 0;
    const bool isq = (blk < NB * NLQ / 4);

    if (isq) {
        r0 = blk * 4;
        ((float4*)&xs[0][0])[t] = ((const float4*)(query + (size_t)r0 * NH))[t];
        Wt = Wtq; bias = bq;
    } else {
        b  = (blk - 256) >> 7;
        j0 = ((blk - 256) & 127) * 4;
        na = nact[b];
        if (j0 >= na) return;
        if (t < 4) ridx[t] = act[b * NLK + ((j0 + t < na) ? (j0 + t) : j0)];
        __syncthreads();
        const int r = t >> 6, c4 = t & 63;
        ((float4*)xs[r])[c4] =
            ((const float4*)(key + ((size_t)b * NLK + ridx[r]) * NH))[c4];
        Wt = Wtk; bias = bk;
    }
    __syncthreads();

    float4 acc[4];
    #pragma unroll
    for (int r = 0; r < 4; ++r) acc[r] = (float4){0.f, 0.f, 0.f, 0.f};

    const int cbase = wave * 64;
    #pragma unroll 4
    for (int cc = 0; cc < 64; ++cc) {
        const int c = cbase + cc;
        const float4 w = *(const float4*)(Wt + (size_t)c * NH + lane * 4);
        #pragma unroll
        for (int r = 0; r < 4; ++r) {
            const float xv = xs[r][c];             // LDS broadcast
            acc[r].x = fmaf(xv, w.x, acc[r].x);
            acc[r].y = fmaf(xv, w.y, acc[r].y);
            acc[r].z = fmaf(xv, w.z, acc[r].z);
            acc[r].w = fmaf(xv, w.w, acc[r].w);
        }
    }
    #pragma unroll
    for (int r = 0; r < 4; ++r) ps[wave][r][lane] = acc[r];
    __syncthreads();

    // combine: thread t -> row r = wave, h-quad l = lane
    const int r = wave, l = lane;
    const float4 p0 = ps[0][r][l], p1 = ps[1][r][l];
    const float4 p2 = ps[2][r][l], p3 = ps[3][r][l];
    const float4 bb = *(const float4*)(bias + l * 4);
    float4 o;
    o.x = (p0.x + p1.x + p2.x + p3.x + bb.x) * SCALE_2LOG2E;
    o.y = (p0.y + p1.y + p2.y + p3.y + bb.y) * SCALE_2LOG2E;
    o.z = (p0.z + p1.z + p2.z + p3.z + bb.z) * SCALE_2LOG2E;
    o.w = (p0.w + p1.w + p2.w + p3.w + bb.w) * SCALE_2LOG2E;

    if (isq) {
        *(float4*)(qp + (size_t)(r0 + r) * NH + l * 4) = o;
    } else if (j0 + r < na) {
        const int j = j0 + r;
        kp_ct[((size_t)b * NH + l * 4 + 0) * NLK + j] = o.x;
        kp_ct[((size_t)b * NH + l * 4 + 1) * NLK + j] = o.y;
        kp_ct[((size_t)b * NH + l * 4 + 2) * NLK + j] = o.z;
        kp_ct[((size_t)b * NH + l * 4 + 3) * NLK + j] = o.w;
    }
}

// ---------------------------------------------------------------------------
// Fused attn. Block = 256 threads (4 waves), 2 q rows, grid = 512.
// Score loop reads kp_ct[b][h][j]: at fixed c a wave loads 512B of
// CONSECUTIVE floats (float2/lane) -> 4 lines/instr, no L1 thrash.
// Thread t: h-half hh=t>>7, slot pair p=t&127 -> slots 2p,2p+1.
// h-halves combined via LDS. Overflow slots (na>256) in a guarded pass 2.
// score'(q,k) = -2*sum_h v[h]*rcp(exp2(q'+k')+1)  (shift-invariant form).
// ---------------------------------------------------------------------------
__global__ __launch_bounds__(256) void attn_kernel(
    const float* __restrict__ qp, const float* __restrict__ kp_ct,
    const float* __restrict__ value, const int* __restrict__ mask,
    const int* __restrict__ act, const int* __restrict__ nact,
    const float* __restrict__ vvec,
    float* __restrict__ out_o, float* __restrict__ out_w)
{
    __shared__ float sc0[NLK], sc1[NLK];
    __shared__ int   actl[NLK];
    __shared__ float pA[256], pB[256], pC[256], pD[256];

    const int blk  = blockIdx.x;
    const int b    = blk >> 7;               // 128 blocks per batch
    const int q0   = (blk & 127) * 2;
    const int t    = threadIdx.x;            // 0..255
    const int lane = t & 63;
    const int wave = t >> 6;

    const int na = nact[b];
    actl[t]       = (t < na)       ? act[b * NLK + t]       : 0;
    actl[t + 256] = (t + 256 < na) ? act[b * NLK + t + 256] : 0;

    // zero masked out_w slots for this block's 2 rows (scatter fills actives)
    float* w0row = out_w + (size_t)(b * NLQ + q0) * NLK;
    float* w1row = w0row + NLK;
    if (!mask[b * NLK + t])       { w0row[t] = 0.f;       w1row[t] = 0.f; }
    if (!mask[b * NLK + t + 256]) { w0row[t + 256] = 0.f; w1row[t + 256] = 0.f; }

    const int hh    = t >> 7;                // h-half 0/1
    const int p     = t & 127;               // slot pair
    const int hbase = hh * 128;
    const float* qr0 = qp + (size_t)(b * NLQ + q0) * NH + hbase;   // uniform
    const float* qr1 = qr0 + NH;                                   // uniform
    const float* vvh = vvec + hbase;                               // uniform
    const float* kb  = kp_ct + ((size_t)b * NH + hbase) * NLK;

    // ---- pass 1: slots 2p, 2p+1 (covers compact slots 0..255) ----
    float a00 = 0.f, a01 = 0.f, a10 = 0.f, a11 = 0.f;
    #pragma unroll 4
    for (int c = 0; c < 128; ++c) {
        const float2 kx = *(const float2*)(kb + (size_t)c * NLK + 2 * p);
        const float qa = qr0[c], qb = qr1[c], vh = vvh[c];
        const float e0 = __builtin_amdgcn_exp2f(qa + kx.x);
        const float e1 = __builtin_amdgcn_exp2f(qa + kx.y);
        const float e2 = __builtin_amdgcn_exp2f(qb + kx.x);
        const float e3 = __builtin_amdgcn_exp2f(qb + kx.y);
        a00 = fmaf(vh, __builtin_amdgcn_rcpf(e0 + 1.f), a00);
        a01 = fmaf(vh, __builtin_amdgcn_rcpf(e1 + 1.f), a01);
        a10 = fmaf(vh, __builtin_amdgcn_rcpf(e2 + 1.f), a10);
        a11 = fmaf(vh, __builtin_amdgcn_rcpf(e3 + 1.f), a11);
    }
    pA[t] = a00; pB[t] = a01; pC[t] = a10; pD[t] = a11;
    __syncthreads();
    if (t < 128) {
        const int s = 2 * t;
        sc0[s]     = (s     < na) ? -2.f * (pA[t] + pA[t + 128]) : -INFINITY;
        sc0[s + 1] = (s + 1 < na) ? -2.f * (pB[t] + pB[t + 128]) : -INFINITY;
    } else {
        const int p2 = t - 128;
        const int s  = 2 * p2;
        sc1[s]     = (s     < na) ? -2.f * (pC[p2] + pC[p2 + 128]) : -INFINITY;
        sc1[s + 1] = (s + 1 < na) ? -2.f * (pD[p2] + pD[p2 + 128]) : -INFINITY;
    }

    // ---- pass 2: overflow slots 256..511 (block-uniform branch) ----
    if (na > 256) {
        __syncthreads();
        a00 = a01 = a10 = a11 = 0.f;
        const int s0 = 256 + 2 * p;
        if (s0 < na) {
            #pragma unroll 4
            for (int c = 0; c < 128; ++c) {
                const float2 kx = *(const float2*)(kb + (size_t)c * NLK + s0);
                const float qa = qr0[c], qb = qr1[c], vh = vvh[c];
                const float e0 = __builtin_amdgcn_exp2f(qa + kx.x);
                const float e1 = __builtin_amdgcn_exp2f(qa + kx.y);
                const float e2 = __builtin_amdgcn_exp2f(qb + kx.x);
                const float e3 = __builtin_amdgcn_exp2f(qb + kx.y);
                a00 = fmaf(vh, __builtin_amdgcn_rcpf(e0 + 1.f), a00);
                a01 = fmaf(vh, __builtin_amdgcn_rcpf(e1 + 1.f), a01);
                a10 = fmaf(vh, __builtin_amdgcn_rcpf(e2 + 1.f), a10);
                a11 = fmaf(vh, __builtin_amdgcn_rcpf(e3 + 1.f), a11);
            }
        }
        pA[t] = a00; pB[t] = a01; pC[t] = a10; pD[t] = a11;
        __syncthreads();
        if (t < 128) {
            const int s = 256 + 2 * t;
            sc0[s]     = (s     < na) ? -2.f * (pA[t] + pA[t + 128]) : -INFINITY;
            sc0[s + 1] = (s + 1 < na) ? -2.f * (pB[t] + pB[t + 128]) : -INFINITY;
        } else {
            const int p2 = t - 128;
            const int s  = 256 + 2 * p2;
            sc1[s]     = (s     < na) ? -2.f * (pC[p2] + pC[p2 + 128]) : -INFINITY;
            sc1[s + 1] = (s + 1 < na) ? -2.f * (pD[p2] + pD[p2 + 128]) : -INFINITY;
        }
    } else {
        sc0[256 + t] = -INFINITY;
        sc1[256 + t] = -INFINITY;
    }
    __syncthreads();

    // ---- softmax: wave 0 -> q row 0, wave 1 -> q row 1 (512 slots) ----
    if (wave < 2) {
        float* row = wave ? sc1 : sc0;
        float vals[8];
        float m = -INFINITY;
        #pragma unroll
        for (int j8 = 0; j8 < 8; ++j8) {
            vals[j8] = row[lane + j8 * 64];
            m = fmaxf(m, vals[j8]);
        }
        #pragma unroll
        for (int s = 32; s >= 1; s >>= 1)
            m = fmaxf(m, __shfl_xor(m, s, 64));
        float sum = 0.0f;
        #pragma unroll
        for (int j8 = 0; j8 < 8; ++j8) {
            vals[j8] = __builtin_amdgcn_exp2f((vals[j8] - m) * LOG2E);
            sum += vals[j8];
        }
        #pragma unroll
        for (int s = 32; s >= 1; s >>= 1)
            sum += __shfl_xor(sum, s, 64);
        const float inv = __builtin_amdgcn_rcpf(sum);
        float* wout = out_w + (size_t)(b * NLQ + q0 + wave) * NLK;
        #pragma unroll
        for (int j8 = 0; j8 < 8; ++j8) {
            const int jj = lane + j8 * 64;
            const float w = vals[j8] * inv;
            row[jj] = w;                      // 0 for jj >= na
            if (jj < na) wout[actl[jj]] = w;  // masked slots stay 0
        }
    }
    __syncthreads();

    // ---- output: thread t = column h, both q rows; weights 0 past na ----
    {
        const float* vb = value + (size_t)b * NLK * NH + t;
        float o0 = 0.f, o1 = 0.f;
        const int n4 = (na + 3) >> 2;
        for (int j4 = 0; j4 < n4; ++j4) {
            const float4 w0 = ((const float4*)sc0)[j4];
            const float4 w1 = ((const float4*)sc1)[j4];
            const int4   aj = ((const int4*)actl)[j4];
            const float v0 = vb[(size_t)aj.x * NH];
            const float v1 = vb[(size_t)aj.y * NH];
            const float v2 = vb[(size_t)aj.z * NH];
            const float v3 = vb[(size_t)aj.w * NH];
            o0 = fmaf(w0.x, v0, o0); o1 = fmaf(w1.x, v0, o1);
            o0 = fmaf(w0.y, v1, o0); o1 = fmaf(w1.y, v1, o1);
            o0 = fmaf(w0.z, v2, o0); o1 = fmaf(w1.z, v2, o1);
            o0 = fmaf(w0.w, v3, o0); o1 = fmaf(w1.w, v3, o1);
        }
        out_o[(size_t)(b * NLQ + q0)     * NH + t] = o0;
        out_o[(size_t)(b * NLQ + q0 + 1) * NH + t] = o1;
    }
}

// ---------------------------------------------------------------------------
extern "C" void kernel_launch(void* const* d_in, const int* in_sizes, int n_in,
                              void* d_out, int out_size, void* d_ws, size_t ws_size,
                              hipStream_t stream) {
    const float* query = (const float*)d_in[0];
    const float* key   = (const float*)d_in[1];
    const float* value = (const float*)d_in[2];
    const int*   mask  = (const int*)  d_in[3];
    const float* Wq    = (const float*)d_in[4];
    const float* bq    = (const float*)d_in[5];
    const float* Wk    = (const float*)d_in[6];
    const float* bk    = (const float*)d_in[7];
    const float* v     = (const float*)d_in[8];
    // d_in[9] (bv) drops out of softmax -> unused

    float* out_o = (float*)d_out;                     // [4,256,256]
    float* out_w = out_o + NB * NLQ * NH;             // [4,256,512]

    float* qp    = (float*)d_ws;                      // [4,256,256] scaled
    float* kp_ct = qp + NB * NLQ * NH;                // [4,256,512] compact-T
    int*   act   = (int*)(kp_ct + NB * NH * NLK);     // [4,512]
    int*   nact  = act + NB * NLK;                    // [4]

    const size_t base = (size_t)(NB * NLQ * NH) + (size_t)(NB * NH * NLK)
                      + NB * NLK + NB;                // floats+ints consumed
    float* wtq;
    if (ws_size >= (base + 2 * NH * NH) * sizeof(float)) {
        wtq = (float*)d_ws + base;                    // workspace tail
    } else {
        // park W^T in the out_w tail; attn (after prep) overwrites out_w
        wtq = out_w + (size_t)NB * NLQ * NLK - 2 * NH * NH;
    }
    float* wtk = wtq + NH * NH;

    setup_kernel<<<36, 256, 0, stream>>>(Wq, Wk, mask, wtq, wtk, act, nact);
    prep_kernel<<<NB * NLQ / 4 + NB * NLK / 4, 256, 0, stream>>>(
        query, key, wtq, bq, wtk, bk, act, nact, qp, kp_ct);
    attn_kernel<<<NB * NLQ / 2, 256, 0, stream>>>(
        qp, kp_ct, value, mask, act, nact, v, out_o, out_w);
}